// Round 3
// baseline (576.009 us; speedup 1.0000x reference)
//
#include <hip/hip_runtime.h>
#include <hip/hip_bf16.h>
#include <stdint.h>

// StaticGraphLSTMCell: B=512, N=21, I=256, H=1024, NT=5
// out = [hy (B*N*H) | cy (B*N*H) | gx_out (N*N)] fp32
//
// Clockwork sparsity: phase(h) = h//128+1 (h=1023 -> 9). c_mask = (t+1)%phase==0.
// Unmasked h need only the outgate. o-tile j (128 wide): g=j>>3, hb=j&7.
// needed(j) = g==3 || (t+1)%(hb+1)==0 || (hb==7 && (t+1)%9==0).
//
// ws layout (bytes):
//   Wc   bf16 [5][4096][1280]   @ 0          (52,428,800)
//   Xc   bf16 [21][512][1280]   @ 52,428,800 (27,525,120)
//   gates bf16 [512][21][4096]  @ 79,953,920 (88,080,384)  (only needed tiles written)
//   gx   f32  [21][21]          @ 168,034,304 (1,764)

typedef __bf16 bf16_t;
typedef __bf16 bf16x8 __attribute__((ext_vector_type(8)));
typedef float f32x4 __attribute__((ext_vector_type(4)));

#define NB 512
#define NN 21
#define NI 256
#define NH 1024
#define KDIM 1280
#define ODIM 4096
#define BNH (512ull * 21 * 1024)

__device__ inline void gld16(const void* g, const void* l) {
  __builtin_amdgcn_global_load_lds(
      (const __attribute__((address_space(1))) unsigned int*)g,
      (__attribute__((address_space(3))) unsigned int*)l, 16, 0, 0);
}

__device__ inline float sigmoid_fast(float x) {
  return 1.0f / (1.0f + __expf(-x));
}
__device__ inline float tanh_fast(float x) {
  float ax = fabsf(x);
  float e = __expf(2.0f * ax);  // inf-safe
  float t = 1.0f - 2.0f / (e + 1.0f);
  return copysignf(t, x);
}

__device__ inline bool tile_needed(int g, int hb, int t1) {
  return (g == 3) || (t1 % (hb + 1) == 0) || (hb == 7 && (t1 % 9) == 0);
}

// ---- gx: L1 row-normalize G; gxw = normalize(G); gxout = normalize(gxw) ----
__global__ void gx_kernel(const float* __restrict__ G, float* __restrict__ gxw,
                          float* __restrict__ gxout) {
  int m = threadIdx.x;
  if (m < NN) {
    float s = 0.f;
    for (int j = 0; j < NN; j++) s += fabsf(G[m * NN + j]);
    s = fmaxf(s, 1e-12f);
    float row[NN];
    float s2 = 0.f;
    for (int j = 0; j < NN; j++) {
      row[j] = G[m * NN + j] / s;
      s2 += fabsf(row[j]);
    }
    s2 = fmaxf(s2, 1e-12f);
    for (int j = 0; j < NN; j++) {
      gxw[m * NN + j] = row[j];
      gxout[m * NN + j] = row[j] / s2;
    }
  }
}

// ---- pack weights (8 elems/thread), skipping rows in dead o-tiles
__global__ __launch_bounds__(256) void pack_w(const float* __restrict__ wih,
                                              const float* __restrict__ whh,
                                              const int* __restrict__ t_ptr,
                                              bf16_t* __restrict__ Wc) {
  int c = blockIdx.x * 256 + threadIdx.x;  // chunk of 8; total 3,276,800
  int k8 = c % (KDIM / 8);
  int row = c / (KDIM / 8);  // tau*4096 + o
  int o = row & (ODIM - 1);
  int t1 = t_ptr[0] + 1;
  if (!tile_needed((o >> 7) >> 3, (o >> 7) & 7, t1)) return;
  int k = k8 * 8;
  const float* src = (k < NI) ? (wih + (size_t)row * NI + k)
                              : (whh + (size_t)row * NH + (k - NI));
  float4 a = *(const float4*)src;
  float4 b = *(const float4*)(src + 4);
  bf16x8 v;
  v[0] = (bf16_t)a.x; v[1] = (bf16_t)a.y; v[2] = (bf16_t)a.z; v[3] = (bf16_t)a.w;
  v[4] = (bf16_t)b.x; v[5] = (bf16_t)b.y; v[6] = (bf16_t)b.z; v[7] = (bf16_t)b.w;
  *(bf16x8*)&Wc[(size_t)c * 8] = v;
}

// ---- pack activations (8 elems/thread)
__global__ __launch_bounds__(256) void pack_x(const float* __restrict__ input,
                                              const float* __restrict__ hx,
                                              bf16_t* __restrict__ Xc) {
  int c = blockIdx.x * 256 + threadIdx.x;  // chunk of 8; total 1,720,320
  int k8 = c % (KDIM / 8);
  int rest = c / (KDIM / 8);  // n*512 + b
  int n = rest / NB;
  int b = rest % NB;
  int k = k8 * 8;
  const float* src = (k < NI) ? (input + ((size_t)b * NN + n) * NI + k)
                              : (hx + ((size_t)b * NN + n) * NH + (k - NI));
  float4 a = *(const float4*)src;
  float4 d = *(const float4*)(src + 4);
  bf16x8 v;
  v[0] = (bf16_t)a.x; v[1] = (bf16_t)a.y; v[2] = (bf16_t)a.z; v[3] = (bf16_t)a.w;
  v[4] = (bf16_t)d.x; v[5] = (bf16_t)d.y; v[6] = (bf16_t)d.z; v[7] = (bf16_t)d.w;
  *(bf16x8*)&Xc[(size_t)c * 8] = v;
}

// ---- GEMM per node n (blockIdx.z), early-exit dead o-tiles
__global__ __launch_bounds__(256) void gemm_bt(const bf16_t* __restrict__ Xc,
                                               const bf16_t* __restrict__ Wc,
                                               const float* __restrict__ bhh,
                                               const int* __restrict__ node_types,
                                               const int* __restrict__ t_ptr,
                                               bf16_t* __restrict__ gates) {
  const int jt = blockIdx.x;  // o-tile
  const int t1 = t_ptr[0] + 1;
  if (!tile_needed(jt >> 3, jt & 7, t1)) return;

  __shared__ bf16_t As[128 * 32];
  __shared__ bf16_t Bs[128 * 32];

  const int n = blockIdx.z;
  const int tau = node_types[n];
  const bf16_t* A = Xc + (size_t)n * NB * KDIM;
  const bf16_t* B = Wc + (size_t)tau * ODIM * KDIM;

  const int tid = threadIdx.x;
  const int m0 = blockIdx.y * 128;
  const int n0 = jt * 128;

  const int lane = tid & 63;
  const int wv = tid >> 6;
  const int wm = (wv >> 1) * 64;
  const int wn = (wv & 1) * 64;
  const int r = lane & 15;
  const int quad = lane >> 4;

  f32x4 acc[4][4];
#pragma unroll
  for (int i = 0; i < 4; i++)
#pragma unroll
    for (int j = 0; j < 4; j++) acc[i][j] = {0.f, 0.f, 0.f, 0.f};

  const int srow = tid >> 2;
  const int schunk = (tid & 3) * 8;

  for (int k0 = 0; k0 < KDIM; k0 += 32) {
    gld16(A + (size_t)(m0 + srow) * KDIM + k0 + schunk, (char*)As + tid * 16);
    gld16(A + (size_t)(m0 + 64 + srow) * KDIM + k0 + schunk, (char*)As + 4096 + tid * 16);
    gld16(B + (size_t)(n0 + srow) * KDIM + k0 + schunk, (char*)Bs + tid * 16);
    gld16(B + (size_t)(n0 + 64 + srow) * KDIM + k0 + schunk, (char*)Bs + 4096 + tid * 16);
    __syncthreads();

    bf16x8 af[4], bfr[4];
#pragma unroll
    for (int i = 0; i < 4; i++)
      af[i] = *(const bf16x8*)&As[(wm + i * 16 + r) * 32 + quad * 8];
#pragma unroll
    for (int j = 0; j < 4; j++)
      bfr[j] = *(const bf16x8*)&Bs[(wn + j * 16 + r) * 32 + quad * 8];
#pragma unroll
    for (int i = 0; i < 4; i++)
#pragma unroll
      for (int j = 0; j < 4; j++)
        acc[i][j] = __builtin_amdgcn_mfma_f32_16x16x32_bf16(af[i], bfr[j], acc[i][j], 0, 0, 0);
    __syncthreads();
  }

  float bv[4];
#pragma unroll
  for (int j = 0; j < 4; j++) bv[j] = bhh[tau * ODIM + n0 + wn + j * 16 + r];
#pragma unroll
  for (int i = 0; i < 4; i++) {
    int brow = m0 + wm + i * 16 + quad * 4;
#pragma unroll
    for (int j = 0; j < 4; j++) {
      int o = n0 + wn + j * 16 + r;
#pragma unroll
      for (int reg = 0; reg < 4; reg++) {
        int b = brow + reg;
        gates[((size_t)b * NN + n) * ODIM + o] = (bf16_t)(acc[i][j][reg] + bv[j]);
      }
    }
  }
}

// ---- fused node-mix + LSTM pointwise.
// block = (hb, b): stage gates[b][n][g*1024 + hb*128 + :] for needed g into LDS,
// mix over n with gx, then LSTM for the 21*128 (m,h) outputs.
__global__ __launch_bounds__(256) void mix_lstm(const bf16_t* __restrict__ gates,
                                                const float* __restrict__ gx,
                                                const float* __restrict__ cx,
                                                const int* __restrict__ t_ptr,
                                                float* __restrict__ out) {
  __shared__ float gxs[NN * NN];
  __shared__ bf16_t gs[NN * 512];  // [n][g*128 + h_local]
  const int tid = threadIdx.x;
  const int hb = blockIdx.x;
  const int b = blockIdx.y;
  const int t1 = t_ptr[0] + 1;
  const bool need_ifc = (t1 % (hb + 1) == 0) || (hb == 7 && (t1 % 9) == 0);

  for (int i = tid; i < NN * NN; i += 256) gxs[i] = gx[i];

  const int ng = need_ifc ? 4 : 1;
  const int total = NN * 16 * ng;
  for (int i = tid; i < total; i += 256) {
    int n = i / (16 * ng);
    int rr = i % (16 * ng);
    int gi = rr / 16;                 // 0..ng-1
    int h8 = rr % 16;
    int g = need_ifc ? gi : 3;
    *(bf16x8*)&gs[n * 512 + g * 128 + h8 * 8] =
        *(const bf16x8*)&gates[((size_t)b * NN + n) * ODIM + g * NH + hb * 128 + h8 * 8];
  }
  __syncthreads();

  const float tf = (float)t1;
  for (int i = tid; i < NN * 16; i += 256) {
    int m = i >> 4;
    int h8 = i & 15;
    float so[8], si[8], sf[8], sc[8];
#pragma unroll
    for (int j = 0; j < 8; j++) { so[j] = 0.f; si[j] = 0.f; sf[j] = 0.f; sc[j] = 0.f; }
    for (int n = 0; n < NN; n++) {
      float w = gxs[m * NN + n];
      bf16x8 vo = *(const bf16x8*)&gs[n * 512 + 3 * 128 + h8 * 8];
#pragma unroll
      for (int j = 0; j < 8; j++) so[j] += w * (float)vo[j];
      if (need_ifc) {
        bf16x8 vi = *(const bf16x8*)&gs[n * 512 + 0 * 128 + h8 * 8];
        bf16x8 vf = *(const bf16x8*)&gs[n * 512 + 1 * 128 + h8 * 8];
        bf16x8 vc = *(const bf16x8*)&gs[n * 512 + 2 * 128 + h8 * 8];
#pragma unroll
        for (int j = 0; j < 8; j++) {
          si[j] += w * (float)vi[j];
          sf[j] += w * (float)vf[j];
          sc[j] += w * (float)vc[j];
        }
      }
    }
    int h = hb * 128 + h8 * 8;
    size_t off = ((size_t)b * NN + m) * NH + h;
    float4 c0 = *(const float4*)&cx[off];
    float4 c1 = *(const float4*)&cx[off + 4];
    float cxv[8] = {c0.x, c0.y, c0.z, c0.w, c1.x, c1.y, c1.z, c1.w};
    float hy[8], cy[8];
#pragma unroll
    for (int j = 0; j < 8; j++) {
      float phase = floorf(((float)(h + j)) / 1023.0f * 8.0f + 1.0f);  // 1..9
      bool cmask = fmodf(tf, phase) < 0.01f;
      float og = sigmoid_fast(so[j]);
      float c;
      if (cmask) {
        float ig = sigmoid_fast(si[j]);
        float fg = sigmoid_fast(sf[j]);
        float cg = tanh_fast(sc[j]);
        c = fg * cxv[j] + ig * cg;
      } else {
        c = cxv[j];
      }
      cy[j] = c;
      hy[j] = og * tanh_fast(c);
    }
    *(float4*)&out[off] = make_float4(hy[0], hy[1], hy[2], hy[3]);
    *(float4*)&out[off + 4] = make_float4(hy[4], hy[5], hy[6], hy[7]);
    *(float4*)&out[BNH + off] = make_float4(cy[0], cy[1], cy[2], cy[3]);
    *(float4*)&out[BNH + off + 4] = make_float4(cy[4], cy[5], cy[6], cy[7]);
  }
}

extern "C" void kernel_launch(void* const* d_in, const int* in_sizes, int n_in,
                              void* d_out, int out_size, void* d_ws, size_t ws_size,
                              hipStream_t stream) {
  const float* input = (const float*)d_in[0];
  const float* hx = (const float*)d_in[1];
  const float* cx = (const float*)d_in[2];
  const float* G = (const float*)d_in[3];
  const float* wih = (const float*)d_in[4];
  const float* whh = (const float*)d_in[5];
  const float* bhh = (const float*)d_in[6];
  const int* node_types = (const int*)d_in[7];
  const int* t = (const int*)d_in[8];
  float* out = (float*)d_out;

  char* ws = (char*)d_ws;
  bf16_t* Wc = (bf16_t*)ws;
  bf16_t* Xc = (bf16_t*)(ws + 52428800);
  bf16_t* gates = (bf16_t*)(ws + 79953920);
  float* gxw = (float*)(ws + 168034304);

  gx_kernel<<<1, 64, 0, stream>>>(G, gxw, out + 2 * BNH);
  pack_w<<<(5 * ODIM * KDIM / 8) / 256, 256, 0, stream>>>(wih, whh, t, Wc);
  pack_x<<<(NN * NB * KDIM / 8) / 256, 256, 0, stream>>>(input, hx, Xc);
  dim3 gg(ODIM / 128, NB / 128, NN);
  gemm_bt<<<gg, 256, 0, stream>>>(Xc, Wc, bhh, node_types, t, gates);
  dim3 gm(NH / 128, NB);
  mix_lstm<<<gm, 256, 0, stream>>>(gates, gxw, cx, t, out);
}